// Round 5
// baseline (2636.575 us; speedup 1.0000x reference)
//
#include <hip/hip_runtime.h>
#include <hip/hip_bf16.h>

typedef __attribute__((ext_vector_type(8))) short bf16x8;
typedef __attribute__((ext_vector_type(4))) float f32x4;

#define HH 96
#define WWD 96
#define CIN 32
#define FF 32
#define TT 12
#define HW (HH*WWD)            // 9216
#define NPOS (8*HW)            // 73728
#define XELEMS (8*TT*HW*CIN)   // 28,311,552
#define HELEMS (NPOS*FF)       // 2,359,296
#define NROWS 768              // 8 batches * 96 rows; one block per row

__device__ __forceinline__ __hip_bfloat16 f2bf(float x) { return __float2bfloat16(x); }

// X fp32 -> bf16, 8 elems/thread
__global__ void cvt_x(const float* __restrict__ X, __hip_bfloat16* __restrict__ Xb) {
    int i = (blockIdx.x * 256 + threadIdx.x) * 8;
    float4 a = *(const float4*)(X + i);
    float4 b = *(const float4*)(X + i + 4);
    __hip_bfloat16 r[8] = { f2bf(a.x), f2bf(a.y), f2bf(a.z), f2bf(a.w),
                            f2bf(b.x), f2bf(b.y), f2bf(b.z), f2bf(b.w) };
    *(bf16x8*)(Xb + i) = *(bf16x8*)r;
}

// Combined weights, B-fragment-major:
//   Wt[(((kk*2+kc)*4+q)*128 + co)*8 + j] = W[kk][ci=kc*32+q*8+j][co]
//   kc=0 -> Wx (x path); kc=1 -> Wx+Wh (h path)
//   (conv(h+x,Wx)+conv(h,Wh) == conv(x,Wx)+conv(h,Wx+Wh))
__global__ void prep_weights(const float* __restrict__ Wx,
                             const float* __restrict__ Wh,
                             __hip_bfloat16* __restrict__ Wt) {
    int idx = blockIdx.x * 256 + threadIdx.x;   // < 73728
    int j  = idx & 7;
    int co = (idx >> 3) & 127;
    int q  = (idx >> 10) & 3;
    int kc = (idx >> 12) & 1;
    int kk = idx >> 13;
    int wi = (kk * 32 + q * 8 + j) * 128 + co;
    float v = Wx[wi];
    if (kc) v += Wh[wi];
    Wt[idx] = f2bf(v);
}

// Persistent-per-row pipelined ConvLSTM: one block per image row, plain
// launch (no cooperative API). Step t at row y needs only h_{t-1} at rows
// y-1..y+1 -> per-row progress flags with agent-scope release/acquire.
// Cell state lives in 12 registers/thread for all 12 steps.
__global__ __launch_bounds__(256, 3) void lstm_pipe(
    const __hip_bfloat16* __restrict__ Xb,    // (8,12,96,96,32) bf16
    const __hip_bfloat16* __restrict__ Wt,    // (9,2,4,128,8) frag-major
    const float* __restrict__ bias,           // (128) fp32
    int* __restrict__ flags,                  // (768) zeroed; flags[r]=t+1 <=> h_t ready
    __hip_bfloat16* __restrict__ hA,          // h ping (h_0, h_2, ...)
    __hip_bfloat16* __restrict__ hB,          // h pong (h_1, h_3, ...)
    float* __restrict__ Out)                  // (8,12,1,96,96,32) fp32
{
    const int tid  = threadIdx.x;
    const int lane = tid & 63;
    const int wave = tid >> 6;     // 0..3
    const int wm   = wave >> 1;    // x-half (48 cols)
    const int wn   = wave & 1;     // f-half (16 channels)
    const int col  = lane & 15;
    const int q    = lane >> 4;

    const int rid = blockIdx.x;    // global row id
    const int bb  = rid / HH;      // batch
    const int yy  = rid % HH;      // image row

    const int f = wn * 16 + col;
    const float bi  = bias[f];
    const float bfg = bias[32 + f];
    const float bc  = bias[64 + f];
    const float bo  = bias[96 + f];

    const __hip_bfloat16* wbase = Wt + q * 1024 + f * 8;

    float cst[3][4] = {};   // register cell state

    for (int t = 0; t < TT; ++t) {
        // ---- wait until valid neighbors have produced h_{t-1}
        if (t > 0) {
            if (tid < 2) {
                bool valid = tid ? (yy < HH - 1) : (yy > 0);
                if (valid) {
                    const int nbr = rid + (tid ? 1 : -1);
                    while (__hip_atomic_load(&flags[nbr], __ATOMIC_ACQUIRE,
                                             __HIP_MEMORY_SCOPE_AGENT) < t) {
                        __builtin_amdgcn_s_sleep(1);
                    }
                }
            }
            __syncthreads();
        }

        const __hip_bfloat16* xslab = Xb + (size_t)(bb * TT + t) * HW * CIN;
        const __hip_bfloat16* Rbuf  = (t & 1) ? hA : hB;   // holds h_{t-1}
        __hip_bfloat16*       Wbuf  = (t & 1) ? hB : hA;   // gets  h_t
        const __hip_bfloat16* hslab = Rbuf + (size_t)bb * HW * CIN;

        f32x4 acc[3][4] = {};   // [mt][gate], D: col=lane&15, row=q*4+reg

        for (int kk = 0; kk < 9; ++kk) {
            const int ky = kk / 3, kx = kk % 3;
            const int yv = yy + ky - 1;               // block-uniform
            const bool yok = ((unsigned)yv < (unsigned)HH);
            const __hip_bfloat16* xrow = xslab + yv * (WWD * CIN);
            const __hip_bfloat16* hrow = hslab + yv * (WWD * CIN);

            bf16x8 ax[3], ah[3];
#pragma unroll
            for (int mt = 0; mt < 3; ++mt) {
                int xv = wm * 48 + mt * 16 + col + kx - 1;
                bool inb = yok & ((unsigned)xv < (unsigned)WWD);
                bf16x8 z = {0,0,0,0,0,0,0,0};
                ax[mt] = z; ah[mt] = z;
                if (inb) {
                    int o = xv * CIN + q * 8;
                    ax[mt] = *(const bf16x8*)(xrow + o);
                    if (t > 0)
                        ah[mt] = *(const bf16x8*)(hrow + o);
                }
            }

#pragma unroll
            for (int kc = 0; kc < 2; ++kc) {
                if (kc == 1 && t == 0) break;   // h==0 at step 0
                const __hip_bfloat16* bb8 = wbase + (kk * 2 + kc) * 4096;
                bf16x8 bf[4];
#pragma unroll
                for (int nt = 0; nt < 4; ++nt)
                    bf[nt] = *(const bf16x8*)(bb8 + nt * 256);
#pragma unroll
                for (int mt = 0; mt < 3; ++mt) {
                    bf16x8 a = (kc == 0) ? ax[mt] : ah[mt];
#pragma unroll
                    for (int nt = 0; nt < 4; ++nt) {
                        acc[mt][nt] = __builtin_amdgcn_mfma_f32_16x16x32_bf16(
                            a, bf[nt], acc[mt][nt], 0, 0, 0);
                    }
                }
            }
        }

        // ---- fused gate epilogue (Keras i,f,c,o; hard_sigmoid gates)
        float* orow = Out + ((size_t)(bb * TT + t) * HW + yy * WWD) * FF;
        __hip_bfloat16* hwrow = Wbuf + ((size_t)bb * HW + yy * WWD) * CIN;

#pragma unroll
        for (int mt = 0; mt < 3; ++mt) {
#pragma unroll
            for (int r = 0; r < 4; ++r) {
                int xo = wm * 48 + mt * 16 + q * 4 + r;
                float zi = acc[mt][0][r] + bi;
                float zf = acc[mt][1][r] + bfg;
                float zc = acc[mt][2][r] + bc;
                float zo = acc[mt][3][r] + bo;
                float ig = fminf(fmaxf(0.2f * zi + 0.5f, 0.f), 1.f);
                float fg = fminf(fmaxf(0.2f * zf + 0.5f, 0.f), 1.f);
                float og = fminf(fmaxf(0.2f * zo + 0.5f, 0.f), 1.f);
                float g  = tanhf(zc);
                float cn = fg * cst[mt][r] + ig * g;
                cst[mt][r] = cn;
                float h = og * tanhf(cn);
                hwrow[xo * CIN + f] = f2bf(h);
                orow[xo * FF + f] = h;
            }
        }

        // ---- publish h_t: per-thread fence, barrier, release-store flag
        __threadfence();
        __syncthreads();
        if (tid == 0)
            __hip_atomic_store(&flags[rid], t + 1, __ATOMIC_RELEASE,
                               __HIP_MEMORY_SCOPE_AGENT);
    }
}

extern "C" void kernel_launch(void* const* d_in, const int* in_sizes, int n_in,
                              void* d_out, int out_size, void* d_ws, size_t ws_size,
                              hipStream_t stream) {
    const float* X    = (const float*)d_in[0];
    const float* Wx   = (const float*)d_in[1];
    const float* Wh   = (const float*)d_in[2];
    const float* bias = (const float*)d_in[3];
    float* Out = (float*)d_out;

    // ws: flags int[768] | Wt bf16 | Xb bf16 | hA bf16 | hB bf16
    char* w = (char*)d_ws;
    int* flags = (int*)w;                      w += NROWS * sizeof(int);
    __hip_bfloat16* Wt = (__hip_bfloat16*)w;   w += 9 * 2 * 4 * 128 * 8 * 2;
    __hip_bfloat16* Xb = (__hip_bfloat16*)w;   w += (size_t)XELEMS * 2;
    __hip_bfloat16* hA = (__hip_bfloat16*)w;   w += (size_t)HELEMS * 2;
    __hip_bfloat16* hB = (__hip_bfloat16*)w;

    hipMemsetAsync(flags, 0, NROWS * sizeof(int), stream);
    cvt_x<<<XELEMS / (256 * 8), 256, 0, stream>>>(X, Xb);
    prep_weights<<<288, 256, 0, stream>>>(Wx, Wh, Wt);
    lstm_pipe<<<NROWS, 256, 0, stream>>>(Xb, Wt, bias, flags, hA, hB, Out);
}

// Round 6
// 410.909 us; speedup vs baseline: 6.4164x; 6.4164x over previous
//
#include <hip/hip_runtime.h>
#include <hip/hip_bf16.h>

typedef __attribute__((ext_vector_type(8))) short bf16x8;
typedef __attribute__((ext_vector_type(4))) float f32x4;

#define HH 96
#define WWD 96
#define CIN 32
#define FF 32
#define TT 12
#define HW (HH*WWD)            // 9216
#define NPOS (8*HW)            // 73728
#define XELEMS (8*TT*HW*CIN)   // 28,311,552
#define HELEMS (NPOS*FF)       // 2,359,296
#define NROWS 768              // one block per (batch,row); 3 blocks/CU

// LDS layout: [slab 0..5][q 0..3][xc 0..97] chunks of 8 bf16 (16B).
// slab 0..2 = x rows ky=0..2, slab 3..5 = h rows. xc = xv+1 (pad at 0 and 97).
#define LSTRIDE (98*8)
#define LIDX(s,q,xc) ((((s)*4+(q))*98 + (xc))*8)

__device__ __forceinline__ __hip_bfloat16 f2bf(float x) { return __float2bfloat16(x); }

// X fp32 -> bf16, 8 elems/thread
__global__ void cvt_x(const float* __restrict__ X, __hip_bfloat16* __restrict__ Xb) {
    int i = (blockIdx.x * 256 + threadIdx.x) * 8;
    float4 a = *(const float4*)(X + i);
    float4 b = *(const float4*)(X + i + 4);
    __hip_bfloat16 r[8] = { f2bf(a.x), f2bf(a.y), f2bf(a.z), f2bf(a.w),
                            f2bf(b.x), f2bf(b.y), f2bf(b.z), f2bf(b.w) };
    *(bf16x8*)(Xb + i) = *(bf16x8*)r;
}

// Combined weights, B-fragment-major:
//   Wt[(((kk*2+kc)*4+q)*128 + co)*8 + j] = W[kk][ci=kc*32+q*8+j][co]
//   kc=0 -> Wx (x path); kc=1 -> Wx+Wh (h path)
//   (conv(h+x,Wx)+conv(h,Wh) == conv(x,Wx)+conv(h,Wx+Wh))
__global__ void prep_weights(const float* __restrict__ Wx,
                             const float* __restrict__ Wh,
                             __hip_bfloat16* __restrict__ Wt) {
    int idx = blockIdx.x * 256 + threadIdx.x;   // < 73728
    int j  = idx & 7;
    int co = (idx >> 3) & 127;
    int q  = (idx >> 10) & 3;
    int kc = (idx >> 12) & 1;
    int kk = idx >> 13;
    int wi = (kk * 32 + q * 8 + j) * 128 + co;
    float v = Wx[wi];
    if (kc) v += Wh[wi];
    Wt[idx] = f2bf(v);
}

// One ConvLSTM step. Per block: one (batch,row). Stage 3 x-rows + 3 h-rows
// into LDS once (coalesced, transposed to conflict-free layout), one barrier,
// then 9*24 MFMAs reading A from LDS / B from L2-resident frag-major Wt.
// XCD swizzle: batch b is handled entirely by XCD b (halo + h reuse in L2).
__global__ __launch_bounds__(256, 3) void lstm_step(
    const __hip_bfloat16* __restrict__ Xb,    // (8,12,96,96,32) bf16
    const __hip_bfloat16* __restrict__ Hin,   // (8,96,96,32) bf16, h_{t-1}
    const __hip_bfloat16* __restrict__ Wt,    // (9,2,4,128,8) frag-major
    const float* __restrict__ bias,           // (128) fp32
    float* __restrict__ Cst,                  // (73728,32) fp32 cell state
    __hip_bfloat16* __restrict__ Hout,        // (8,96,96,32) bf16, h_t
    float* __restrict__ Out,                  // (8,12,1,96,96,32) fp32
    int t)
{
    __shared__ __align__(16) ushort lds[6 * 4 * 98 * 8];   // 37632 B

    const int tid  = threadIdx.x;
    const int lane = tid & 63;
    const int wave = tid >> 6;     // 0..3
    const int wm   = wave >> 1;    // x-half (48 cols)
    const int wn   = wave & 1;     // f-half (16 channels)
    const int col  = lane & 15;
    const int q    = lane >> 4;

    // XCD swizzle: consecutive hardware blocks -> same batch on one XCD
    const int rid = (blockIdx.x & 7) * 96 + (blockIdx.x >> 3);
    const int bb  = rid / HH;      // batch (== XCD id)
    const int yy  = rid % HH;      // image row

    const __hip_bfloat16* xslab = Xb + (size_t)(bb * TT + t) * HW * CIN;
    const __hip_bfloat16* hslab = Hin + (size_t)bb * HW * CIN;

    // ---- prefetch cell state (consumed only in epilogue)
    const int f = wn * 16 + col;
    const int prow = bb * HW + yy * WWD;
    float cold[3][4];
#pragma unroll
    for (int mt = 0; mt < 3; ++mt)
#pragma unroll
        for (int r = 0; r < 4; ++r) {
            int xo = wm * 48 + mt * 16 + q * 4 + r;
            cold[mt][r] = (t > 0) ? Cst[(size_t)(prow + xo) * FF + f] : 0.f;
        }

    // ---- zero the x-halo pad chunks (xc = 0 and 97 for all slabs, q)
    if (tid < 48) {
        int s = tid >> 3, rem = tid & 7, qq = rem >> 1, e = rem & 1;
        bf16x8 z = {0,0,0,0,0,0,0,0};
        *(bf16x8*)&lds[LIDX(s, qq, e * 97)] = z;
    }

    // ---- stage 6 slabs (3 x-rows, 3 h-rows), 384 16B-chunks each,
    //      transposing [xv][q] (global) -> [q][xv] (LDS)
#pragma unroll
    for (int it = 0; it < 9; ++it) {
        int c = it * 256 + tid;            // < 2304
        int s = c / 384, i = c % 384;
        int xv = i >> 2, qq = i & 3;
        int ky = (s >= 3) ? s - 3 : s;
        int yv = yy + ky - 1;
        bool isH = (s >= 3);
        if ((unsigned)yv < (unsigned)HH && !(isH && t == 0)) {
            const __hip_bfloat16* src = isH ? hslab : xslab;
            bf16x8 v = *(const bf16x8*)(src + (size_t)yv * (WWD * CIN) + xv * CIN + qq * 8);
            *(bf16x8*)&lds[LIDX(s, qq, xv + 1)] = v;
        }
    }
    __syncthreads();

    const __hip_bfloat16* wbase = Wt + q * 1024 + f * 8;

    f32x4 acc[3][4] = {};   // [mt][gate], D: col=lane&15, row=q*4+reg

    for (int kk = 0; kk < 9; ++kk) {
        const int ky = kk / 3, kx = kk % 3;
        const int yv = yy + ky - 1;
        if ((unsigned)yv >= (unsigned)HH) continue;   // block-uniform skip

        bf16x8 ax[3], ah[3];
#pragma unroll
        for (int mt = 0; mt < 3; ++mt) {
            int xc = wm * 48 + mt * 16 + col + kx;    // xv+1, in [0,97]
            ax[mt] = *(const bf16x8*)&lds[LIDX(ky, q, xc)];
            if (t > 0)
                ah[mt] = *(const bf16x8*)&lds[LIDX(3 + ky, q, xc)];
        }

#pragma unroll
        for (int kc = 0; kc < 2; ++kc) {
            if (kc == 1 && t == 0) break;   // h==0 at step 0
            const __hip_bfloat16* bb8 = wbase + (kk * 2 + kc) * 4096;
            bf16x8 bf[4];
#pragma unroll
            for (int nt = 0; nt < 4; ++nt)
                bf[nt] = *(const bf16x8*)(bb8 + nt * 256);
#pragma unroll
            for (int mt = 0; mt < 3; ++mt) {
                bf16x8 a = (kc == 0) ? ax[mt] : ah[mt];
#pragma unroll
                for (int nt = 0; nt < 4; ++nt) {
                    acc[mt][nt] = __builtin_amdgcn_mfma_f32_16x16x32_bf16(
                        a, bf[nt], acc[mt][nt], 0, 0, 0);
                }
            }
        }
    }

    // ---- fused gate epilogue (Keras i,f,c,o; hard_sigmoid gates)
    const float bi  = bias[f];
    const float bfg = bias[32 + f];
    const float bc  = bias[64 + f];
    const float bo  = bias[96 + f];

    float* orow = Out + ((size_t)(bb * TT + t) * HW + yy * WWD) * FF;
    __hip_bfloat16* hwrow = Hout + (size_t)prow * CIN;

#pragma unroll
    for (int mt = 0; mt < 3; ++mt) {
#pragma unroll
        for (int r = 0; r < 4; ++r) {
            int xo = wm * 48 + mt * 16 + q * 4 + r;
            float zi = acc[mt][0][r] + bi;
            float zf = acc[mt][1][r] + bfg;
            float zc = acc[mt][2][r] + bc;
            float zo = acc[mt][3][r] + bo;
            float ig = fminf(fmaxf(0.2f * zi + 0.5f, 0.f), 1.f);
            float fg = fminf(fmaxf(0.2f * zf + 0.5f, 0.f), 1.f);
            float og = fminf(fmaxf(0.2f * zo + 0.5f, 0.f), 1.f);
            float g  = tanhf(zc);
            float cn = fg * cold[mt][r] + ig * g;
            Cst[(size_t)(prow + xo) * FF + f] = cn;
            float h = og * tanhf(cn);
            hwrow[xo * CIN + f] = f2bf(h);
            orow[xo * FF + f] = h;
        }
    }
}

extern "C" void kernel_launch(void* const* d_in, const int* in_sizes, int n_in,
                              void* d_out, int out_size, void* d_ws, size_t ws_size,
                              hipStream_t stream) {
    const float* X    = (const float*)d_in[0];
    const float* Wx   = (const float*)d_in[1];
    const float* Wh   = (const float*)d_in[2];
    const float* bias = (const float*)d_in[3];
    float* Out = (float*)d_out;

    // ws: Wt bf16 | Xb bf16 | hA bf16 | hB bf16 | Cst fp32
    char* w = (char*)d_ws;
    __hip_bfloat16* Wt = (__hip_bfloat16*)w;   w += 9 * 2 * 4 * 128 * 8 * 2;
    __hip_bfloat16* Xb = (__hip_bfloat16*)w;   w += (size_t)XELEMS * 2;
    __hip_bfloat16* hA = (__hip_bfloat16*)w;   w += (size_t)HELEMS * 2;
    __hip_bfloat16* hB = (__hip_bfloat16*)w;   w += (size_t)HELEMS * 2;
    float* Cst = (float*)w;

    cvt_x<<<XELEMS / (256 * 8), 256, 0, stream>>>(X, Xb);
    prep_weights<<<288, 256, 0, stream>>>(Wx, Wh, Wt);
    for (int t = 0; t < TT; ++t) {
        __hip_bfloat16* hin  = (t & 1) ? hB : hA;   // t=0: unused (guarded)
        __hip_bfloat16* hout = (t & 1) ? hA : hB;
        lstm_step<<<NROWS, 256, 0, stream>>>(Xb, hin, Wt, bias, Cst, hout, Out, t);
    }
}